// Round 1
// baseline (4135.784 us; speedup 1.0000x reference)
//
#include <hip/hip_runtime.h>
#include <cstdint>
#include <cstddef>

// Problem shape (fixed by setup_inputs)
#define NND   10000     // nodes per graph
#define NED   160000    // edges per graph
#define NB    8         // batch
#define NF    256       // in features
#define NHID  64        // hidden per head
#define HEADS 8
#define F1    512       // HEADS*NHID
#define NCLS  64        // out classes

#define ALPHA_SLOPE 0.2f
#define OUT_SLOPE   0.01f
#define EPS         1e-16f

// ---------------- ws layout (in floats) ----------------
static const size_t OFF_WCAT = 0;                            // [256][512]
static const size_t OFF_H1   = OFF_WCAT + 256 * 512;         // [N][512]
static const size_t OFF_AGG1 = OFF_H1 + (size_t)NND * F1;    // [N][512]  (zero region start; becomes xc)
static const size_t OFF_DEN1 = OFF_AGG1 + (size_t)NND * F1;  // [N][8]
static const size_t OFF_AGG2 = OFF_DEN1 + (size_t)NND * 8;   // [N][64]
static const size_t OFF_DEN2 = OFF_AGG2 + (size_t)NND * 64;  // [N]       (zero region end)
static const size_t OFF_AS1  = OFF_DEN2 + (size_t)NND;       // [N][8]
static const size_t OFF_AD1  = OFF_AS1 + (size_t)NND * 8;    // [N][8]
static const size_t OFF_H2   = OFF_AD1 + (size_t)NND * 8;    // [N][64]
static const size_t OFF_AS2  = OFF_H2 + (size_t)NND * 64;    // [N]
static const size_t OFF_AD2  = OFF_AS2 + (size_t)NND;        // [N]
static const size_t ZERO_FLOATS = (size_t)NND * (F1 + 8 + 64 + 1);  // agg1+den1+agg2+den2

// ---------------- kernels ----------------

// Rearrange W_heads [8][256][64] -> Wcat [256][512] with col = h*64+j
__global__ __launch_bounds__(256) void k_wcat(const float* __restrict__ Whd,
                                              float* __restrict__ Wcat) {
  int idx = blockIdx.x * 256 + threadIdx.x;   // 131072 total
  int k = idx >> 9, c = idx & 511;
  Wcat[idx] = Whd[(c >> 6) * (NF * NHID) + k * NHID + (c & 63)];
}

// f32 tiled GEMM: C[M,N] = A[M,K] * B[K,N], row-major, ld == logical dims.
// BM=128, BN=64, BK=16, 256 threads, 8x4 micro-tile.
#define BM 128
#define BN 64
#define BK 16
__global__ __launch_bounds__(256) void k_gemm(const float* __restrict__ A,
                                              const float* __restrict__ B,
                                              float* __restrict__ C,
                                              int M, int N, int K) {
  __shared__ float As[BK][BM + 4];   // pitch 132 (16B-aligned rows)
  __shared__ float Bs[BK][BN + 4];   // pitch 68
  const int m0 = blockIdx.x * BM;
  const int n0 = blockIdx.y * BN;
  const int tid = threadIdx.x;
  const int tx = tid & 15, ty = tid >> 4;
  float acc[8][4] = {};

  for (int k0 = 0; k0 < K; k0 += BK) {
    // A tile: 128x16 floats = 512 float4 loads
#pragma unroll
    for (int u = 0; u < 2; ++u) {
      int f = tid + u * 256;
      int r = f >> 2, kc = (f & 3) * 4;
      int gm = m0 + r;
      float4 v = make_float4(0.f, 0.f, 0.f, 0.f);
      if (gm < M) v = *(const float4*)(A + (size_t)gm * K + k0 + kc);
      As[kc + 0][r] = v.x; As[kc + 1][r] = v.y;
      As[kc + 2][r] = v.z; As[kc + 3][r] = v.w;
    }
    // B tile: 16x64 floats = 256 float4 loads
    {
      int k = tid >> 4, c = (tid & 15) * 4;
      float4 v = *(const float4*)(B + (size_t)(k0 + k) * N + n0 + c);
      *(float4*)&Bs[k][c] = v;
    }
    __syncthreads();
#pragma unroll
    for (int k = 0; k < BK; ++k) {
      float ra[8], rb[4];
#pragma unroll
      for (int i = 0; i < 8; ++i) ra[i] = As[k][ty * 8 + i];
#pragma unroll
      for (int j = 0; j < 4; ++j) rb[j] = Bs[k][tx * 4 + j];
#pragma unroll
      for (int i = 0; i < 8; ++i)
#pragma unroll
        for (int j = 0; j < 4; ++j)
          acc[i][j] += ra[i] * rb[j];
    }
    __syncthreads();
  }
#pragma unroll
  for (int i = 0; i < 8; ++i) {
    int gm = m0 + ty * 8 + i;
    if (gm < M) {
      float4 v = make_float4(acc[i][0], acc[i][1], acc[i][2], acc[i][3]);
      *(float4*)(C + (size_t)gm * N + n0 + tx * 4) = v;
    }
  }
}

// alpha projections for layer 1: one wave per (node, head)
__global__ __launch_bounds__(256) void k_alpha1(const float* __restrict__ h1,
                                                const float* __restrict__ a_heads,
                                                float* __restrict__ as_,
                                                float* __restrict__ ad_) {
  int lane = threadIdx.x & 63;
  int wid = (blockIdx.x * blockDim.x + threadIdx.x) >> 6;
  int nw = (gridDim.x * blockDim.x) >> 6;
  const int total = NND * HEADS;
  for (int t = wid; t < total; t += nw) {
    int n = t >> 3, h = t & 7;
    float hv = h1[(size_t)n * F1 + h * NHID + lane];
    float s = hv * a_heads[h * 128 + lane];
    float d = hv * a_heads[h * 128 + 64 + lane];
#pragma unroll
    for (int off = 32; off; off >>= 1) {
      s += __shfl_down(s, off);
      d += __shfl_down(d, off);
    }
    if (lane == 0) { as_[n * 8 + h] = s; ad_[n * 8 + h] = d; }
  }
}

// layer-1 edge scatter: one wave per (edge, head); 64 lanes = 64 features
__global__ __launch_bounds__(256) void k_edge1(const int* __restrict__ src,
                                               const int* __restrict__ dst,
                                               const float* __restrict__ h1,
                                               const float* __restrict__ as_,
                                               const float* __restrict__ ad_,
                                               float* __restrict__ agg,
                                               float* __restrict__ denom) {
  int lane = threadIdx.x & 63;
  int wid = (blockIdx.x * blockDim.x + threadIdx.x) >> 6;
  int nw = (gridDim.x * blockDim.x) >> 6;
  const int total = NED * HEADS;
  for (int t = wid; t < total; t += nw) {
    int e = t >> 3, h = t & 7;
    int s = src[e], d = dst[e];
    float sc = as_[s * 8 + h] + ad_[d * 8 + h];
    float lr = sc >= 0.f ? sc : ALPHA_SLOPE * sc;
    float ev = expf(-lr);
    float hv = h1[(size_t)d * F1 + h * NHID + lane];
    atomicAdd(&agg[(size_t)s * F1 + h * NHID + lane], ev * hv);
    if (lane == 0) atomicAdd(&denom[s * 8 + h], ev);
  }
}

// finalize layer 1: xc = elu(agg / (denom + eps)), in-place on agg
__global__ __launch_bounds__(256) void k_final1(float* __restrict__ agg,
                                                const float* __restrict__ denom) {
  int i = blockIdx.x * 256 + threadIdx.x;   // N*512 total
  int n = i >> 9;
  int h = (i & 511) >> 6;
  float v = agg[i] / (denom[n * 8 + h] + EPS);
  agg[i] = v > 0.f ? v : expm1f(v);
}

// alpha projections for layer 2: one wave per node
__global__ __launch_bounds__(256) void k_alpha2(const float* __restrict__ h2,
                                                const float* __restrict__ a_out,
                                                float* __restrict__ as_,
                                                float* __restrict__ ad_) {
  int lane = threadIdx.x & 63;
  int wid = (blockIdx.x * blockDim.x + threadIdx.x) >> 6;
  int nw = (gridDim.x * blockDim.x) >> 6;
  for (int n = wid; n < NND; n += nw) {
    float hv = h2[(size_t)n * NCLS + lane];
    float s = hv * a_out[lane];
    float d = hv * a_out[64 + lane];
#pragma unroll
    for (int off = 32; off; off >>= 1) {
      s += __shfl_down(s, off);
      d += __shfl_down(d, off);
    }
    if (lane == 0) { as_[n] = s; ad_[n] = d; }
  }
}

// layer-2 edge scatter: one wave per edge
__global__ __launch_bounds__(256) void k_edge2(const int* __restrict__ src,
                                               const int* __restrict__ dst,
                                               const float* __restrict__ h2,
                                               const float* __restrict__ as_,
                                               const float* __restrict__ ad_,
                                               float* __restrict__ agg,
                                               float* __restrict__ denom) {
  int lane = threadIdx.x & 63;
  int wid = (blockIdx.x * blockDim.x + threadIdx.x) >> 6;
  int nw = (gridDim.x * blockDim.x) >> 6;
  for (int e = wid; e < NED; e += nw) {
    int s = src[e], d = dst[e];
    float sc = as_[s] + ad_[d];
    float lr = sc >= 0.f ? sc : ALPHA_SLOPE * sc;
    float ev = expf(-lr);
    float hv = h2[(size_t)d * NCLS + lane];
    atomicAdd(&agg[(size_t)s * NCLS + lane], ev * hv);
    if (lane == 0) atomicAdd(&denom[s], ev);
  }
}

// finalize layer 2: out = leaky_relu(agg / (denom + eps), 0.01)
__global__ __launch_bounds__(256) void k_final2(const float* __restrict__ agg,
                                                const float* __restrict__ denom,
                                                float* __restrict__ out) {
  int i = blockIdx.x * 256 + threadIdx.x;   // N*64 total
  int n = i >> 6;
  float v = agg[i] / (denom[n] + EPS);
  out[i] = v >= 0.f ? v : OUT_SLOPE * v;
}

// ---------------- launcher ----------------
extern "C" void kernel_launch(void* const* d_in, const int* in_sizes, int n_in,
                              void* d_out, int out_size, void* d_ws, size_t ws_size,
                              hipStream_t stream) {
  const float* x       = (const float*)d_in[0];   // [B,N,256]
  const int*   ei      = (const int*)d_in[1];     // [B,2,E]
  const float* W_heads = (const float*)d_in[2];   // [8,256,64]
  const float* a_heads = (const float*)d_in[3];   // [8,128]
  const float* W_out   = (const float*)d_in[4];   // [512,64]
  const float* a_out   = (const float*)d_in[5];   // [128]
  float* out = (float*)d_out;

  float* ws = (float*)d_ws;
  float* Wcat  = ws + OFF_WCAT;
  float* h1    = ws + OFF_H1;
  float* agg1  = ws + OFF_AGG1;   // becomes xc after k_final1
  float* den1  = ws + OFF_DEN1;
  float* agg2  = ws + OFF_AGG2;
  float* den2  = ws + OFF_DEN2;
  float* as1   = ws + OFF_AS1;
  float* ad1   = ws + OFF_AD1;
  float* h2    = ws + OFF_H2;
  float* as2   = ws + OFF_AS2;
  float* ad2   = ws + OFF_AD2;

  // W_heads -> Wcat [256][512], once per call
  k_wcat<<<512, 256, 0, stream>>>(W_heads, Wcat);

  for (int b = 0; b < NB; ++b) {
    const float* xb  = x + (size_t)b * NND * NF;
    const int*   srb = ei + (size_t)b * 2 * NED;
    const int*   dsb = srb + NED;
    float*       ob  = out + (size_t)b * NND * NCLS;

    // zero agg1/den1/agg2/den2 (contiguous region)
    hipMemsetAsync(agg1, 0, ZERO_FLOATS * sizeof(float), stream);

    // layer 1
    k_gemm<<<dim3((NND + BM - 1) / BM, F1 / BN), 256, 0, stream>>>(
        xb, Wcat, h1, NND, F1, NF);
    k_alpha1<<<2048, 256, 0, stream>>>(h1, a_heads, as1, ad1);
    k_edge1<<<4096, 256, 0, stream>>>(srb, dsb, h1, as1, ad1, agg1, den1);
    k_final1<<<(NND * F1) / 256, 256, 0, stream>>>(agg1, den1);

    // layer 2
    k_gemm<<<dim3((NND + BM - 1) / BM, NCLS / BN), 256, 0, stream>>>(
        agg1, W_out, h2, NND, NCLS, F1);
    k_alpha2<<<640, 256, 0, stream>>>(h2, a_out, as2, ad2);
    k_edge2<<<2048, 256, 0, stream>>>(srb, dsb, h2, as2, ad2, agg2, den2);
    k_final2<<<(NND * NCLS) / 256, 256, 0, stream>>>(agg2, den2, ob);
  }
  (void)in_sizes; (void)n_in; (void)out_size; (void)ws_size;
}

// Round 2
// 2118.218 us; speedup vs baseline: 1.9525x; 1.9525x over previous
//
#include <hip/hip_runtime.h>
#include <cstdint>
#include <cstddef>

// Problem shape (fixed by setup_inputs)
#define NND   10000     // nodes per graph
#define NED   160000    // edges per graph
#define NB    8         // batch
#define NF    256       // in features
#define NHID  64        // hidden per head
#define HEADS 8
#define F1    512       // HEADS*NHID
#define NCLS  64        // out classes

#define ALPHA_SLOPE 0.2f
#define OUT_SLOPE   0.01f
#define EPS         1e-16f

// ---------------- ws layout ----------------
// float region
static const size_t OFF_WCAT = 0;                              // [256][512]
static const size_t OFF_H1   = OFF_WCAT + 256 * 512;           // [N][512]
static const size_t OFF_XC   = OFF_H1 + (size_t)NND * F1;      // [N][512]
static const size_t OFF_AS1  = OFF_XC + (size_t)NND * F1;      // [N][8]
static const size_t OFF_AD1  = OFF_AS1 + (size_t)NND * HEADS;  // [N][8]
static const size_t OFF_H2   = OFF_AD1 + (size_t)NND * HEADS;  // [N][64]
static const size_t OFF_AS2  = OFF_H2 + (size_t)NND * NCLS;    // [N]
static const size_t OFF_AD2  = OFF_AS2 + (size_t)NND;          // [N]
static const size_t OFF_INT  = OFF_AD2 + (size_t)NND;          // int region start
// int region (relative to (int*)(ws + OFF_INT))
static const size_t IOFF_COUNTS = 0;                                 // [B][N]
static const size_t IOFF_ROWS   = IOFF_COUNTS + (size_t)NB * NND;    // [B][N+1]
static const size_t IOFF_CUR    = IOFF_ROWS + (size_t)NB * (NND + 1);// [B][N]
static const size_t IOFF_DST    = IOFF_CUR + (size_t)NB * NND;       // [B][E]

// ---------------- kernels ----------------

// Rearrange W_heads [8][256][64] -> Wcat [256][512] with col = h*64+j
__global__ __launch_bounds__(256) void k_wcat(const float* __restrict__ Whd,
                                              float* __restrict__ Wcat) {
  int idx = blockIdx.x * 256 + threadIdx.x;   // 131072 total
  int k = idx >> 9, c = idx & 511;
  Wcat[idx] = Whd[(c >> 6) * (NF * NHID) + k * NHID + (c & 63)];
}

// f32 tiled GEMM: C[M,N] = A[M,K] * B[K,N], row-major.
#define BM 128
#define BN 64
#define BK 16
__global__ __launch_bounds__(256) void k_gemm(const float* __restrict__ A,
                                              const float* __restrict__ B,
                                              float* __restrict__ C,
                                              int M, int N, int K) {
  __shared__ float As[BK][BM + 4];
  __shared__ float Bs[BK][BN + 4];
  const int m0 = blockIdx.x * BM;
  const int n0 = blockIdx.y * BN;
  const int tid = threadIdx.x;
  const int tx = tid & 15, ty = tid >> 4;
  float acc[8][4] = {};

  for (int k0 = 0; k0 < K; k0 += BK) {
#pragma unroll
    for (int u = 0; u < 2; ++u) {
      int f = tid + u * 256;
      int r = f >> 2, kc = (f & 3) * 4;
      int gm = m0 + r;
      float4 v = make_float4(0.f, 0.f, 0.f, 0.f);
      if (gm < M) v = *(const float4*)(A + (size_t)gm * K + k0 + kc);
      As[kc + 0][r] = v.x; As[kc + 1][r] = v.y;
      As[kc + 2][r] = v.z; As[kc + 3][r] = v.w;
    }
    {
      int k = tid >> 4, c = (tid & 15) * 4;
      float4 v = *(const float4*)(B + (size_t)(k0 + k) * N + n0 + c);
      *(float4*)&Bs[k][c] = v;
    }
    __syncthreads();
#pragma unroll
    for (int k = 0; k < BK; ++k) {
      float ra[8], rb[4];
#pragma unroll
      for (int i = 0; i < 8; ++i) ra[i] = As[k][ty * 8 + i];
#pragma unroll
      for (int j = 0; j < 4; ++j) rb[j] = Bs[k][tx * 4 + j];
#pragma unroll
      for (int i = 0; i < 8; ++i)
#pragma unroll
        for (int j = 0; j < 4; ++j)
          acc[i][j] += ra[i] * rb[j];
    }
    __syncthreads();
  }
#pragma unroll
  for (int i = 0; i < 8; ++i) {
    int gm = m0 + ty * 8 + i;
    if (gm < M) {
      float4 v = make_float4(acc[i][0], acc[i][1], acc[i][2], acc[i][3]);
      *(float4*)(C + (size_t)gm * N + n0 + tx * 4) = v;
    }
  }
}

// ---- counting sort (all batches in one launch each) ----

// histogram of src
__global__ __launch_bounds__(256) void k_hist(const int* __restrict__ ei,
                                              int* __restrict__ counts) {
  int b = blockIdx.y;
  int e = blockIdx.x * 256 + threadIdx.x;
  if (e < NED) {
    int s = ei[(size_t)b * 2 * NED + e];
    atomicAdd(&counts[b * NND + s], 1);
  }
}

// exclusive scan of counts -> row_start (and cursor copy); one block per batch
__global__ __launch_bounds__(1024) void k_scan(const int* __restrict__ counts,
                                               int* __restrict__ rows,
                                               int* __restrict__ cursor) {
  __shared__ int lds[1024];
  __shared__ int s_carry;
  const int b = blockIdx.x;
  const int tid = threadIdx.x;
  const int* cb = counts + b * NND;
  int* rb = rows + b * (NND + 1);
  int* ub = cursor + b * NND;
  if (tid == 0) s_carry = 0;
  __syncthreads();
  for (int base = 0; base < NND; base += 1024) {
    int i = base + tid;
    int v = (i < NND) ? cb[i] : 0;
    lds[tid] = v;
    __syncthreads();
#pragma unroll
    for (int off = 1; off < 1024; off <<= 1) {
      int t = (tid >= off) ? lds[tid - off] : 0;
      __syncthreads();
      lds[tid] += t;
      __syncthreads();
    }
    int incl = lds[tid];
    int carry = s_carry;
    if (i < NND) {
      int excl = carry + incl - v;
      rb[i] = excl;
      ub[i] = excl;
    }
    __syncthreads();
    if (tid == 1023) s_carry = carry + incl;
    __syncthreads();
  }
  if (tid == 0) rb[NND] = s_carry;
}

// scatter dst into src-sorted order
__global__ __launch_bounds__(256) void k_scatter(const int* __restrict__ ei,
                                                 int* __restrict__ cursor,
                                                 int* __restrict__ dst_s) {
  int b = blockIdx.y;
  int e = blockIdx.x * 256 + threadIdx.x;
  if (e < NED) {
    int s = ei[(size_t)b * 2 * NED + e];
    int d = ei[(size_t)b * 2 * NED + NED + e];
    int pos = atomicAdd(&cursor[b * NND + s], 1);
    dst_s[(size_t)b * NED + pos] = d;
  }
}

// alpha projections layer 1: one wave per (node, head)
__global__ __launch_bounds__(256) void k_alpha1(const float* __restrict__ h1,
                                                const float* __restrict__ a_heads,
                                                float* __restrict__ as_,
                                                float* __restrict__ ad_) {
  int lane = threadIdx.x & 63;
  int wid = (blockIdx.x * blockDim.x + threadIdx.x) >> 6;
  int nw = (gridDim.x * blockDim.x) >> 6;
  const int total = NND * HEADS;
  for (int t = wid; t < total; t += nw) {
    int n = t >> 3, h = t & 7;
    float hv = h1[(size_t)n * F1 + h * NHID + lane];
    float s = hv * a_heads[h * 128 + lane];
    float d = hv * a_heads[h * 128 + 64 + lane];
#pragma unroll
    for (int off = 32; off; off >>= 1) {
      s += __shfl_down(s, off);
      d += __shfl_down(d, off);
    }
    if (lane == 0) { as_[n * 8 + h] = s; ad_[n * 8 + h] = d; }
  }
}

// layer-1 CSR aggregation + finalize: one wave per (node, head), lane=feature
__global__ __launch_bounds__(256) void k_agg1(const int* __restrict__ rows,
                                              const int* __restrict__ dst_s,
                                              const float* __restrict__ h1,
                                              const float* __restrict__ as_,
                                              const float* __restrict__ ad_,
                                              float* __restrict__ xc) {
  int lane = threadIdx.x & 63;
  int wid = (blockIdx.x * 256 + threadIdx.x) >> 6;
  if (wid >= NND * HEADS) return;
  int n = wid >> 3, h = wid & 7;
  float asv = as_[n * 8 + h];
  int beg = rows[n], end = rows[n + 1];
  float acc = 0.f, den = 0.f;
  for (int i = beg; i < end; ++i) {
    int d = dst_s[i];
    float sc = asv + ad_[d * 8 + h];
    sc = sc >= 0.f ? sc : ALPHA_SLOPE * sc;
    float ev = expf(-sc);
    float hv = h1[(size_t)d * F1 + h * NHID + lane];
    acc = fmaf(ev, hv, acc);
    den += ev;
  }
  float v = acc / (den + EPS);
  xc[(size_t)n * F1 + h * NHID + lane] = v > 0.f ? v : expm1f(v);
}

// alpha projections layer 2: one wave per node
__global__ __launch_bounds__(256) void k_alpha2(const float* __restrict__ h2,
                                                const float* __restrict__ a_out,
                                                float* __restrict__ as_,
                                                float* __restrict__ ad_) {
  int lane = threadIdx.x & 63;
  int wid = (blockIdx.x * blockDim.x + threadIdx.x) >> 6;
  int nw = (gridDim.x * blockDim.x) >> 6;
  for (int n = wid; n < NND; n += nw) {
    float hv = h2[(size_t)n * NCLS + lane];
    float s = hv * a_out[lane];
    float d = hv * a_out[64 + lane];
#pragma unroll
    for (int off = 32; off; off >>= 1) {
      s += __shfl_down(s, off);
      d += __shfl_down(d, off);
    }
    if (lane == 0) { as_[n] = s; ad_[n] = d; }
  }
}

// layer-2 CSR aggregation + finalize: one wave per node, lane=feature
__global__ __launch_bounds__(256) void k_agg2(const int* __restrict__ rows,
                                              const int* __restrict__ dst_s,
                                              const float* __restrict__ h2,
                                              const float* __restrict__ as_,
                                              const float* __restrict__ ad_,
                                              float* __restrict__ out) {
  int lane = threadIdx.x & 63;
  int wid = (blockIdx.x * 256 + threadIdx.x) >> 6;
  if (wid >= NND) return;
  int n = wid;
  float asv = as_[n];
  int beg = rows[n], end = rows[n + 1];
  float acc = 0.f, den = 0.f;
  for (int i = beg; i < end; ++i) {
    int d = dst_s[i];
    float sc = asv + ad_[d];
    sc = sc >= 0.f ? sc : ALPHA_SLOPE * sc;
    float ev = expf(-sc);
    float hv = h2[(size_t)d * NCLS + lane];
    acc = fmaf(ev, hv, acc);
    den += ev;
  }
  float v = acc / (den + EPS);
  out[(size_t)n * NCLS + lane] = v >= 0.f ? v : OUT_SLOPE * v;
}

// ---------------- launcher ----------------
extern "C" void kernel_launch(void* const* d_in, const int* in_sizes, int n_in,
                              void* d_out, int out_size, void* d_ws, size_t ws_size,
                              hipStream_t stream) {
  const float* x       = (const float*)d_in[0];   // [B,N,256]
  const int*   ei      = (const int*)d_in[1];     // [B,2,E]
  const float* W_heads = (const float*)d_in[2];   // [8,256,64]
  const float* a_heads = (const float*)d_in[3];   // [8,128]
  const float* W_out   = (const float*)d_in[4];   // [512,64]
  const float* a_out   = (const float*)d_in[5];   // [128]
  float* out = (float*)d_out;

  float* ws = (float*)d_ws;
  float* Wcat = ws + OFF_WCAT;
  float* h1   = ws + OFF_H1;
  float* xc   = ws + OFF_XC;
  float* as1  = ws + OFF_AS1;
  float* ad1  = ws + OFF_AD1;
  float* h2   = ws + OFF_H2;
  float* as2  = ws + OFF_AS2;
  float* ad2  = ws + OFF_AD2;
  int* ib      = (int*)(ws + OFF_INT);
  int* counts  = ib + IOFF_COUNTS;
  int* rows    = ib + IOFF_ROWS;
  int* cursor  = ib + IOFF_CUR;
  int* dst_s   = ib + IOFF_DST;

  // weights rearrange (once)
  k_wcat<<<512, 256, 0, stream>>>(W_heads, Wcat);

  // ---- counting sort for all batches ----
  hipMemsetAsync(counts, 0, (size_t)NB * NND * sizeof(int), stream);
  k_hist<<<dim3((NED + 255) / 256, NB), 256, 0, stream>>>(ei, counts);
  k_scan<<<NB, 1024, 0, stream>>>(counts, rows, cursor);
  k_scatter<<<dim3((NED + 255) / 256, NB), 256, 0, stream>>>(ei, cursor, dst_s);

  for (int b = 0; b < NB; ++b) {
    const float* xb = x + (size_t)b * NND * NF;
    const int*   rb = rows + (size_t)b * (NND + 1);
    const int*   db = dst_s + (size_t)b * NED;
    float*       ob = out + (size_t)b * NND * NCLS;

    // layer 1
    k_gemm<<<dim3((NND + BM - 1) / BM, F1 / BN), 256, 0, stream>>>(
        xb, Wcat, h1, NND, F1, NF);
    k_alpha1<<<2048, 256, 0, stream>>>(h1, a_heads, as1, ad1);
    k_agg1<<<(NND * HEADS * 64) / 256, 256, 0, stream>>>(rb, db, h1, as1, ad1, xc);

    // layer 2
    k_gemm<<<dim3((NND + BM - 1) / BM, NCLS / BN), 256, 0, stream>>>(
        xc, W_out, h2, NND, NCLS, F1);
    k_alpha2<<<640, 256, 0, stream>>>(h2, a_out, as2, ad2);
    k_agg2<<<(NND * 64) / 256, 256, 0, stream>>>(rb, db, h2, as2, ad2, ob);
  }
  (void)in_sizes; (void)n_in; (void)out_size; (void)ws_size;
}

// Round 3
// 1569.486 us; speedup vs baseline: 2.6351x; 1.3496x over previous
//
#include <hip/hip_runtime.h>
#include <cstdint>
#include <cstddef>

// Problem shape (fixed by setup_inputs)
#define NND   10000     // nodes per graph
#define NED   160000    // edges per graph
#define NB    8         // batch
#define NF    256       // in features
#define NHID  64        // hidden per head
#define HEADS 8
#define F1    512       // HEADS*NHID
#define NCLS  64        // out classes

#define ALPHA_SLOPE 0.2f
#define OUT_SLOPE   0.01f
#define EPS         1e-16f

// ---------------- ws layout ----------------
// float region
static const size_t OFF_WCAT = 0;                              // [256][512]
static const size_t OFF_H1   = OFF_WCAT + 256 * 512;           // [N][512]
static const size_t OFF_XC   = OFF_H1 + (size_t)NND * F1;      // [N][512]
static const size_t OFF_AS1  = OFF_XC + (size_t)NND * F1;      // [N][8]
static const size_t OFF_AD1  = OFF_AS1 + (size_t)NND * HEADS;  // [N][8]
static const size_t OFF_H2   = OFF_AD1 + (size_t)NND * HEADS;  // [N][64]
static const size_t OFF_AS2  = OFF_H2 + (size_t)NND * NCLS;    // [N]
static const size_t OFF_AD2  = OFF_AS2 + (size_t)NND;          // [N]
static const size_t OFF_EV1  = OFF_AD2 + (size_t)NND;          // [E][8]
static const size_t OFF_EV2  = OFF_EV1 + (size_t)NED * HEADS;  // [E]
static const size_t OFF_INT  = OFF_EV2 + (size_t)NED;          // int region start
// int region (relative to (int*)(ws + OFF_INT))
static const size_t IOFF_COUNTS = 0;                                 // [B][N]
static const size_t IOFF_ROWS   = IOFF_COUNTS + (size_t)NB * NND;    // [B][N+1]
static const size_t IOFF_CUR    = IOFF_ROWS + (size_t)NB * (NND + 1);// [B][N]
static const size_t IOFF_EDGE   = IOFF_CUR + (size_t)NB * NND;       // [B][E] int2 (even offset)

// ---------------- kernels ----------------

// Rearrange W_heads [8][256][64] -> Wcat [256][512] with col = h*64+j
__global__ __launch_bounds__(256) void k_wcat(const float* __restrict__ Whd,
                                              float* __restrict__ Wcat) {
  int idx = blockIdx.x * 256 + threadIdx.x;   // 131072 total
  int k = idx >> 9, c = idx & 511;
  Wcat[idx] = Whd[(c >> 6) * (NF * NHID) + k * NHID + (c & 63)];
}

// f32 tiled GEMM: C[M,N] = A[M,K] * B[K,N], row-major.
#define BM 128
#define BN 64
#define BK 16
__global__ __launch_bounds__(256) void k_gemm(const float* __restrict__ A,
                                              const float* __restrict__ B,
                                              float* __restrict__ C,
                                              int M, int N, int K) {
  __shared__ float As[BK][BM + 4];
  __shared__ float Bs[BK][BN + 4];
  const int m0 = blockIdx.x * BM;
  const int n0 = blockIdx.y * BN;
  const int tid = threadIdx.x;
  const int tx = tid & 15, ty = tid >> 4;
  float acc[8][4] = {};

  for (int k0 = 0; k0 < K; k0 += BK) {
#pragma unroll
    for (int u = 0; u < 2; ++u) {
      int f = tid + u * 256;
      int r = f >> 2, kc = (f & 3) * 4;
      int gm = m0 + r;
      float4 v = make_float4(0.f, 0.f, 0.f, 0.f);
      if (gm < M) v = *(const float4*)(A + (size_t)gm * K + k0 + kc);
      As[kc + 0][r] = v.x; As[kc + 1][r] = v.y;
      As[kc + 2][r] = v.z; As[kc + 3][r] = v.w;
    }
    {
      int k = tid >> 4, c = (tid & 15) * 4;
      float4 v = *(const float4*)(B + (size_t)(k0 + k) * N + n0 + c);
      *(float4*)&Bs[k][c] = v;
    }
    __syncthreads();
#pragma unroll
    for (int k = 0; k < BK; ++k) {
      float ra[8], rb[4];
#pragma unroll
      for (int i = 0; i < 8; ++i) ra[i] = As[k][ty * 8 + i];
#pragma unroll
      for (int j = 0; j < 4; ++j) rb[j] = Bs[k][tx * 4 + j];
#pragma unroll
      for (int i = 0; i < 8; ++i)
#pragma unroll
        for (int j = 0; j < 4; ++j)
          acc[i][j] += ra[i] * rb[j];
    }
    __syncthreads();
  }
#pragma unroll
  for (int i = 0; i < 8; ++i) {
    int gm = m0 + ty * 8 + i;
    if (gm < M) {
      float4 v = make_float4(acc[i][0], acc[i][1], acc[i][2], acc[i][3]);
      *(float4*)(C + (size_t)gm * N + n0 + tx * 4) = v;
    }
  }
}

// ---- counting sort (all batches in one launch each) ----

__global__ __launch_bounds__(256) void k_hist(const int* __restrict__ ei,
                                              int* __restrict__ counts) {
  int b = blockIdx.y;
  int e = blockIdx.x * 256 + threadIdx.x;
  if (e < NED) {
    int s = ei[(size_t)b * 2 * NED + e];
    atomicAdd(&counts[b * NND + s], 1);
  }
}

// exclusive scan of counts -> row_start (and cursor copy); one block per batch
__global__ __launch_bounds__(1024) void k_scan(const int* __restrict__ counts,
                                               int* __restrict__ rows,
                                               int* __restrict__ cursor) {
  __shared__ int lds[1024];
  __shared__ int s_carry;
  const int b = blockIdx.x;
  const int tid = threadIdx.x;
  const int* cb = counts + b * NND;
  int* rb = rows + b * (NND + 1);
  int* ub = cursor + b * NND;
  if (tid == 0) s_carry = 0;
  __syncthreads();
  for (int base = 0; base < NND; base += 1024) {
    int i = base + tid;
    int v = (i < NND) ? cb[i] : 0;
    lds[tid] = v;
    __syncthreads();
#pragma unroll
    for (int off = 1; off < 1024; off <<= 1) {
      int t = (tid >= off) ? lds[tid - off] : 0;
      __syncthreads();
      lds[tid] += t;
      __syncthreads();
    }
    int incl = lds[tid];
    int carry = s_carry;
    if (i < NND) {
      int excl = carry + incl - v;
      rb[i] = excl;
      ub[i] = excl;
    }
    __syncthreads();
    if (tid == 1023) s_carry = carry + incl;
    __syncthreads();
  }
  if (tid == 0) rb[NND] = s_carry;
}

// scatter (src,dst) into src-sorted order as packed int2
__global__ __launch_bounds__(256) void k_scatter(const int* __restrict__ ei,
                                                 int* __restrict__ cursor,
                                                 int2* __restrict__ eb) {
  int b = blockIdx.y;
  int e = blockIdx.x * 256 + threadIdx.x;
  if (e < NED) {
    int s = ei[(size_t)b * 2 * NED + e];
    int d = ei[(size_t)b * 2 * NED + NED + e];
    int pos = atomicAdd(&cursor[b * NND + s], 1);
    eb[(size_t)b * NED + pos] = make_int2(s, d);
  }
}

// alpha projections layer 1: one wave per (node, head)
__global__ __launch_bounds__(256) void k_alpha1(const float* __restrict__ h1,
                                                const float* __restrict__ a_heads,
                                                float* __restrict__ as_,
                                                float* __restrict__ ad_) {
  int lane = threadIdx.x & 63;
  int wid = (blockIdx.x * blockDim.x + threadIdx.x) >> 6;
  int nw = (gridDim.x * blockDim.x) >> 6;
  const int total = NND * HEADS;
  for (int t = wid; t < total; t += nw) {
    int n = t >> 3, h = t & 7;
    float hv = h1[(size_t)n * F1 + h * NHID + lane];
    float s = hv * a_heads[h * 128 + lane];
    float d = hv * a_heads[h * 128 + 64 + lane];
#pragma unroll
    for (int off = 32; off; off >>= 1) {
      s += __shfl_down(s, off);
      d += __shfl_down(d, off);
    }
    if (lane == 0) { as_[n * 8 + h] = s; ad_[n * 8 + h] = d; }
  }
}

// layer-1 edge scores on sorted edges: ev[i*8+h] = exp(-leaky(as[s,h]+ad[d,h]))
__global__ __launch_bounds__(256) void k_escore1(const int2* __restrict__ eb,
                                                 const float* __restrict__ as_,
                                                 const float* __restrict__ ad_,
                                                 float* __restrict__ ev) {
  int t = blockIdx.x * 256 + threadIdx.x;   // E*8 total
  int i = t >> 3, h = t & 7;
  int2 sd = eb[i];
  float sc = as_[sd.x * 8 + h] + ad_[sd.y * 8 + h];
  sc = sc >= 0.f ? sc : ALPHA_SLOPE * sc;
  ev[t] = expf(-sc);
}

// layer-1 CSR aggregation + finalize: one wave per node (all heads).
// lane l owns features l*8..l*8+7, all within head (l>>3).
__global__ __launch_bounds__(256) void k_agg1(const int* __restrict__ rows,
                                              const int2* __restrict__ eb,
                                              const float* __restrict__ h1,
                                              const float* __restrict__ ev,
                                              float* __restrict__ xc) {
  int lane = threadIdx.x & 63;
  int n = (blockIdx.x * 256 + threadIdx.x) >> 6;
  if (n >= NND) return;
  const int hh = lane >> 3;
  int beg = rows[n], end = rows[n + 1];
  float acc[8] = {};
  float den = 0.f;
  int i = beg;
  for (; i + 2 <= end; i += 2) {
    int d0 = eb[i].y, d1 = eb[i + 1].y;
    float e0 = ev[(size_t)i * 8 + hh];
    float e1 = ev[(size_t)(i + 1) * 8 + hh];
    const float* r0 = h1 + (size_t)d0 * F1 + lane * 8;
    const float* r1 = h1 + (size_t)d1 * F1 + lane * 8;
    float4 x0 = *(const float4*)r0, y0 = *(const float4*)(r0 + 4);
    float4 x1 = *(const float4*)r1, y1 = *(const float4*)(r1 + 4);
    acc[0] = fmaf(e0, x0.x, acc[0]); acc[1] = fmaf(e0, x0.y, acc[1]);
    acc[2] = fmaf(e0, x0.z, acc[2]); acc[3] = fmaf(e0, x0.w, acc[3]);
    acc[4] = fmaf(e0, y0.x, acc[4]); acc[5] = fmaf(e0, y0.y, acc[5]);
    acc[6] = fmaf(e0, y0.z, acc[6]); acc[7] = fmaf(e0, y0.w, acc[7]);
    acc[0] = fmaf(e1, x1.x, acc[0]); acc[1] = fmaf(e1, x1.y, acc[1]);
    acc[2] = fmaf(e1, x1.z, acc[2]); acc[3] = fmaf(e1, x1.w, acc[3]);
    acc[4] = fmaf(e1, y1.x, acc[4]); acc[5] = fmaf(e1, y1.y, acc[5]);
    acc[6] = fmaf(e1, y1.z, acc[6]); acc[7] = fmaf(e1, y1.w, acc[7]);
    den += e0 + e1;
  }
  if (i < end) {
    int d0 = eb[i].y;
    float e0 = ev[(size_t)i * 8 + hh];
    const float* r0 = h1 + (size_t)d0 * F1 + lane * 8;
    float4 x0 = *(const float4*)r0, y0 = *(const float4*)(r0 + 4);
    acc[0] = fmaf(e0, x0.x, acc[0]); acc[1] = fmaf(e0, x0.y, acc[1]);
    acc[2] = fmaf(e0, x0.z, acc[2]); acc[3] = fmaf(e0, x0.w, acc[3]);
    acc[4] = fmaf(e0, y0.x, acc[4]); acc[5] = fmaf(e0, y0.y, acc[5]);
    acc[6] = fmaf(e0, y0.z, acc[6]); acc[7] = fmaf(e0, y0.w, acc[7]);
    den += e0;
  }
  float inv = 1.f / (den + EPS);
  float o[8];
#pragma unroll
  for (int j = 0; j < 8; ++j) {
    float v = acc[j] * inv;
    o[j] = v > 0.f ? v : expm1f(v);
  }
  float* w = xc + (size_t)n * F1 + lane * 8;
  *(float4*)w = make_float4(o[0], o[1], o[2], o[3]);
  *(float4*)(w + 4) = make_float4(o[4], o[5], o[6], o[7]);
}

// alpha projections layer 2: one wave per node
__global__ __launch_bounds__(256) void k_alpha2(const float* __restrict__ h2,
                                                const float* __restrict__ a_out,
                                                float* __restrict__ as_,
                                                float* __restrict__ ad_) {
  int lane = threadIdx.x & 63;
  int wid = (blockIdx.x * blockDim.x + threadIdx.x) >> 6;
  int nw = (gridDim.x * blockDim.x) >> 6;
  for (int n = wid; n < NND; n += nw) {
    float hv = h2[(size_t)n * NCLS + lane];
    float s = hv * a_out[lane];
    float d = hv * a_out[64 + lane];
#pragma unroll
    for (int off = 32; off; off >>= 1) {
      s += __shfl_down(s, off);
      d += __shfl_down(d, off);
    }
    if (lane == 0) { as_[n] = s; ad_[n] = d; }
  }
}

// layer-2 edge scores
__global__ __launch_bounds__(256) void k_escore2(const int2* __restrict__ eb,
                                                 const float* __restrict__ as_,
                                                 const float* __restrict__ ad_,
                                                 float* __restrict__ ev) {
  int i = blockIdx.x * 256 + threadIdx.x;   // E total
  int2 sd = eb[i];
  float sc = as_[sd.x] + ad_[sd.y];
  sc = sc >= 0.f ? sc : ALPHA_SLOPE * sc;
  ev[i] = expf(-sc);
}

// layer-2 CSR aggregation + finalize: one wave per node, lane = feature
__global__ __launch_bounds__(256) void k_agg2(const int* __restrict__ rows,
                                              const int2* __restrict__ eb,
                                              const float* __restrict__ h2,
                                              const float* __restrict__ ev,
                                              float* __restrict__ out) {
  int lane = threadIdx.x & 63;
  int n = (blockIdx.x * 256 + threadIdx.x) >> 6;
  if (n >= NND) return;
  int beg = rows[n], end = rows[n + 1];
  float acc = 0.f, den = 0.f;
  int i = beg;
  for (; i + 2 <= end; i += 2) {
    int d0 = eb[i].y, d1 = eb[i + 1].y;
    float e0 = ev[i], e1 = ev[i + 1];
    float h0 = h2[(size_t)d0 * NCLS + lane];
    float h1v = h2[(size_t)d1 * NCLS + lane];
    acc = fmaf(e0, h0, acc);
    acc = fmaf(e1, h1v, acc);
    den += e0 + e1;
  }
  if (i < end) {
    int d0 = eb[i].y;
    float e0 = ev[i];
    acc = fmaf(e0, h2[(size_t)d0 * NCLS + lane], acc);
    den += e0;
  }
  float v = acc / (den + EPS);
  out[(size_t)n * NCLS + lane] = v >= 0.f ? v : OUT_SLOPE * v;
}

// ---------------- launcher ----------------
extern "C" void kernel_launch(void* const* d_in, const int* in_sizes, int n_in,
                              void* d_out, int out_size, void* d_ws, size_t ws_size,
                              hipStream_t stream) {
  const float* x       = (const float*)d_in[0];   // [B,N,256]
  const int*   ei      = (const int*)d_in[1];     // [B,2,E]
  const float* W_heads = (const float*)d_in[2];   // [8,256,64]
  const float* a_heads = (const float*)d_in[3];   // [8,128]
  const float* W_out   = (const float*)d_in[4];   // [512,64]
  const float* a_out   = (const float*)d_in[5];   // [128]
  float* out = (float*)d_out;

  float* ws = (float*)d_ws;
  float* Wcat = ws + OFF_WCAT;
  float* h1   = ws + OFF_H1;
  float* xc   = ws + OFF_XC;
  float* as1  = ws + OFF_AS1;
  float* ad1  = ws + OFF_AD1;
  float* h2   = ws + OFF_H2;
  float* as2  = ws + OFF_AS2;
  float* ad2  = ws + OFF_AD2;
  float* ev1  = ws + OFF_EV1;
  float* ev2  = ws + OFF_EV2;
  int* ib      = (int*)(ws + OFF_INT);
  int* counts  = ib + IOFF_COUNTS;
  int* rows    = ib + IOFF_ROWS;
  int* cursor  = ib + IOFF_CUR;
  int2* eb     = (int2*)(ib + IOFF_EDGE);

  // weights rearrange (once)
  k_wcat<<<512, 256, 0, stream>>>(W_heads, Wcat);

  // ---- counting sort for all batches ----
  hipMemsetAsync(counts, 0, (size_t)NB * NND * sizeof(int), stream);
  k_hist<<<dim3((NED + 255) / 256, NB), 256, 0, stream>>>(ei, counts);
  k_scan<<<NB, 1024, 0, stream>>>(counts, rows, cursor);
  k_scatter<<<dim3((NED + 255) / 256, NB), 256, 0, stream>>>(ei, cursor, eb);

  for (int b = 0; b < NB; ++b) {
    const float* xb = x + (size_t)b * NND * NF;
    const int*   rb = rows + (size_t)b * (NND + 1);
    const int2*  ebb = eb + (size_t)b * NED;
    float*       ob = out + (size_t)b * NND * NCLS;

    // layer 1
    k_gemm<<<dim3((NND + BM - 1) / BM, F1 / BN), 256, 0, stream>>>(
        xb, Wcat, h1, NND, F1, NF);
    k_alpha1<<<2048, 256, 0, stream>>>(h1, a_heads, as1, ad1);
    k_escore1<<<(NED * HEADS) / 256, 256, 0, stream>>>(ebb, as1, ad1, ev1);
    k_agg1<<<(NND * 64 + 255) / 256, 256, 0, stream>>>(rb, ebb, h1, ev1, xc);

    // layer 2
    k_gemm<<<dim3((NND + BM - 1) / BM, NCLS / BN), 256, 0, stream>>>(
        xc, W_out, h2, NND, NCLS, F1);
    k_alpha2<<<640, 256, 0, stream>>>(h2, a_out, as2, ad2);
    k_escore2<<<NED / 256, 256, 0, stream>>>(ebb, as2, ad2, ev2);
    k_agg2<<<(NND * 64 + 255) / 256, 256, 0, stream>>>(rb, ebb, h2, ev2, ob);
  }
  (void)in_sizes; (void)n_in; (void)out_size; (void)ws_size;
}

// Round 4
// 1416.861 us; speedup vs baseline: 2.9190x; 1.1077x over previous
//
#include <hip/hip_runtime.h>
#include <cstdint>
#include <cstddef>

// Problem shape (fixed by setup_inputs)
#define NND   10000     // nodes per graph
#define NED   160000    // edges per graph
#define NB    8         // batch
#define NF    256       // in features
#define NHID  64        // hidden per head
#define HEADS 8
#define F1    512       // HEADS*NHID
#define NCLS  64        // out classes

#define ALPHA_SLOPE 0.2f
#define OUT_SLOPE   0.01f
#define EPS         1e-16f

// ---------------- ws layout ----------------
// float region
static const size_t OFF_WCAT = 0;                              // [256][512]
static const size_t OFF_H1   = OFF_WCAT + 256 * 512;           // [N][512]
static const size_t OFF_XC   = OFF_H1 + (size_t)NND * F1;      // [N][512]
static const size_t OFF_AS1  = OFF_XC + (size_t)NND * F1;      // [N][8]
static const size_t OFF_AD1  = OFF_AS1 + (size_t)NND * HEADS;  // [N][8]
static const size_t OFF_H2   = OFF_AD1 + (size_t)NND * HEADS;  // [N][64]
static const size_t OFF_AS2  = OFF_H2 + (size_t)NND * NCLS;    // [N]
static const size_t OFF_AD2  = OFF_AS2 + (size_t)NND;          // [N]
static const size_t OFF_INT  = OFF_AD2 + (size_t)NND;          // int region start
// int region (relative to (int*)(ws + OFF_INT))
static const size_t IOFF_COUNTS = 0;                                 // [B][N]
static const size_t IOFF_ROWS   = IOFF_COUNTS + (size_t)NB * NND;    // [B][N+1]
static const size_t IOFF_CUR    = IOFF_ROWS + (size_t)NB * (NND + 1);// [B][N]
static const size_t IOFF_DST    = IOFF_CUR + (size_t)NB * NND;       // [B][E]

// ---------------- kernels ----------------

// Rearrange W_heads [8][256][64] -> Wcat [256][512] with col = h*64+j
__global__ __launch_bounds__(256) void k_wcat(const float* __restrict__ Whd,
                                              float* __restrict__ Wcat) {
  int idx = blockIdx.x * 256 + threadIdx.x;   // 131072 total
  int k = idx >> 9, c = idx & 511;
  Wcat[idx] = Whd[(c >> 6) * (NF * NHID) + k * NHID + (c & 63)];
}

// f32 tiled GEMM with fused alpha-projection epilogue.
// C[M,N] = A[M,K]*B[K,N]; block col n0 = blockIdx.y*64 == one head slice.
// as_[gm*astr + h] = sum_j C[gm][h*64+j] * avec[h*128 + j]
// ad_[gm*astr + h] = sum_j C[gm][h*64+j] * avec[h*128 + 64 + j]
#define BM 128
#define BN 64
#define BK 16
__global__ __launch_bounds__(256) void k_gemm_a(const float* __restrict__ A,
                                                const float* __restrict__ B,
                                                float* __restrict__ C,
                                                int M, int N, int K,
                                                const float* __restrict__ avec,
                                                float* __restrict__ as_,
                                                float* __restrict__ ad_,
                                                int astr) {
  __shared__ float As[BK][BM + 4];
  __shared__ float Bs[BK][BN + 4];
  const int m0 = blockIdx.x * BM;
  const int h  = blockIdx.y;
  const int n0 = h * BN;
  const int tid = threadIdx.x;
  const int tx = tid & 15, ty = tid >> 4;
  float acc[8][4] = {};

  for (int k0 = 0; k0 < K; k0 += BK) {
#pragma unroll
    for (int u = 0; u < 2; ++u) {
      int f = tid + u * 256;
      int r = f >> 2, kc = (f & 3) * 4;
      int gm = m0 + r;
      float4 v = make_float4(0.f, 0.f, 0.f, 0.f);
      if (gm < M) v = *(const float4*)(A + (size_t)gm * K + k0 + kc);
      As[kc + 0][r] = v.x; As[kc + 1][r] = v.y;
      As[kc + 2][r] = v.z; As[kc + 3][r] = v.w;
    }
    {
      int k = tid >> 4, c = (tid & 15) * 4;
      float4 v = *(const float4*)(B + (size_t)(k0 + k) * N + n0 + c);
      *(float4*)&Bs[k][c] = v;
    }
    __syncthreads();
#pragma unroll
    for (int k = 0; k < BK; ++k) {
      float ra[8], rb[4];
#pragma unroll
      for (int i = 0; i < 8; ++i) ra[i] = As[k][ty * 8 + i];
#pragma unroll
      for (int j = 0; j < 4; ++j) rb[j] = Bs[k][tx * 4 + j];
#pragma unroll
      for (int i = 0; i < 8; ++i)
#pragma unroll
        for (int j = 0; j < 4; ++j)
          acc[i][j] += ra[i] * rb[j];
    }
    __syncthreads();
  }

  // C write + fused alpha projection
  const float4 a_s = *(const float4*)(avec + h * 128 + tx * 4);
  const float4 a_d = *(const float4*)(avec + h * 128 + 64 + tx * 4);
#pragma unroll
  for (int i = 0; i < 8; ++i) {
    int gm = m0 + ty * 8 + i;
    float ps = acc[i][0] * a_s.x + acc[i][1] * a_s.y +
               acc[i][2] * a_s.z + acc[i][3] * a_s.w;
    float pd = acc[i][0] * a_d.x + acc[i][1] * a_d.y +
               acc[i][2] * a_d.z + acc[i][3] * a_d.w;
#pragma unroll
    for (int off = 8; off; off >>= 1) {
      ps += __shfl_xor(ps, off, 16);
      pd += __shfl_xor(pd, off, 16);
    }
    if (gm < M) {
      float4 v = make_float4(acc[i][0], acc[i][1], acc[i][2], acc[i][3]);
      *(float4*)(C + (size_t)gm * N + n0 + tx * 4) = v;
      if (tx == 0) {
        as_[(size_t)gm * astr + h] = ps;
        ad_[(size_t)gm * astr + h] = pd;
      }
    }
  }
}

// ---- counting sort (all batches in one launch each) ----

__global__ __launch_bounds__(256) void k_hist(const int* __restrict__ ei,
                                              int* __restrict__ counts) {
  int b = blockIdx.y;
  int e = blockIdx.x * 256 + threadIdx.x;
  if (e < NED) {
    int s = ei[(size_t)b * 2 * NED + e];
    atomicAdd(&counts[b * NND + s], 1);
  }
}

// exclusive scan of counts -> row_start (and cursor copy); one block per batch
__global__ __launch_bounds__(1024) void k_scan(const int* __restrict__ counts,
                                               int* __restrict__ rows,
                                               int* __restrict__ cursor) {
  __shared__ int lds[1024];
  __shared__ int s_carry;
  const int b = blockIdx.x;
  const int tid = threadIdx.x;
  const int* cb = counts + b * NND;
  int* rb = rows + b * (NND + 1);
  int* ub = cursor + b * NND;
  if (tid == 0) s_carry = 0;
  __syncthreads();
  for (int base = 0; base < NND; base += 1024) {
    int i = base + tid;
    int v = (i < NND) ? cb[i] : 0;
    lds[tid] = v;
    __syncthreads();
#pragma unroll
    for (int off = 1; off < 1024; off <<= 1) {
      int t = (tid >= off) ? lds[tid - off] : 0;
      __syncthreads();
      lds[tid] += t;
      __syncthreads();
    }
    int incl = lds[tid];
    int carry = s_carry;
    if (i < NND) {
      int excl = carry + incl - v;
      rb[i] = excl;
      ub[i] = excl;
    }
    __syncthreads();
    if (tid == 1023) s_carry = carry + incl;
    __syncthreads();
  }
  if (tid == 0) rb[NND] = s_carry;
}

// scatter dst into src-sorted order (dst only; src == segment id in CSR)
__global__ __launch_bounds__(256) void k_scatter(const int* __restrict__ ei,
                                                 int* __restrict__ cursor,
                                                 int* __restrict__ dst_s) {
  int b = blockIdx.y;
  int e = blockIdx.x * 256 + threadIdx.x;
  if (e < NED) {
    int s = ei[(size_t)b * 2 * NED + e];
    int d = ei[(size_t)b * 2 * NED + NED + e];
    int pos = atomicAdd(&cursor[b * NND + s], 1);
    dst_s[(size_t)b * NED + pos] = d;
  }
}

// layer-1 CSR aggregation, fused score + finalize: one wave per node.
// lane l owns features l*8..l*8+7, all within head (l>>3).
__global__ __launch_bounds__(256) void k_agg1(const int* __restrict__ rows,
                                              const int* __restrict__ dst_s,
                                              const float* __restrict__ h1,
                                              const float* __restrict__ as_,
                                              const float* __restrict__ ad_,
                                              float* __restrict__ xc) {
  int lane = threadIdx.x & 63;
  int n = (blockIdx.x * 256 + threadIdx.x) >> 6;
  if (n >= NND) return;
  const int hh = lane >> 3;
  const float asv = as_[n * 8 + hh];
  int beg = rows[n], end = rows[n + 1];
  float acc[8] = {};
  float den = 0.f;
  int i = beg;
  for (; i + 2 <= end; i += 2) {
    int d0 = dst_s[i], d1 = dst_s[i + 1];
    float s0 = asv + ad_[d0 * 8 + hh];
    float s1 = asv + ad_[d1 * 8 + hh];
    s0 = s0 >= 0.f ? s0 : ALPHA_SLOPE * s0;
    s1 = s1 >= 0.f ? s1 : ALPHA_SLOPE * s1;
    float e0 = __expf(-s0), e1 = __expf(-s1);
    const float* r0 = h1 + (size_t)d0 * F1 + lane * 8;
    const float* r1 = h1 + (size_t)d1 * F1 + lane * 8;
    float4 x0 = *(const float4*)r0, y0 = *(const float4*)(r0 + 4);
    float4 x1 = *(const float4*)r1, y1 = *(const float4*)(r1 + 4);
    acc[0] = fmaf(e0, x0.x, acc[0]); acc[1] = fmaf(e0, x0.y, acc[1]);
    acc[2] = fmaf(e0, x0.z, acc[2]); acc[3] = fmaf(e0, x0.w, acc[3]);
    acc[4] = fmaf(e0, y0.x, acc[4]); acc[5] = fmaf(e0, y0.y, acc[5]);
    acc[6] = fmaf(e0, y0.z, acc[6]); acc[7] = fmaf(e0, y0.w, acc[7]);
    acc[0] = fmaf(e1, x1.x, acc[0]); acc[1] = fmaf(e1, x1.y, acc[1]);
    acc[2] = fmaf(e1, x1.z, acc[2]); acc[3] = fmaf(e1, x1.w, acc[3]);
    acc[4] = fmaf(e1, y1.x, acc[4]); acc[5] = fmaf(e1, y1.y, acc[5]);
    acc[6] = fmaf(e1, y1.z, acc[6]); acc[7] = fmaf(e1, y1.w, acc[7]);
    den += e0 + e1;
  }
  if (i < end) {
    int d0 = dst_s[i];
    float s0 = asv + ad_[d0 * 8 + hh];
    s0 = s0 >= 0.f ? s0 : ALPHA_SLOPE * s0;
    float e0 = __expf(-s0);
    const float* r0 = h1 + (size_t)d0 * F1 + lane * 8;
    float4 x0 = *(const float4*)r0, y0 = *(const float4*)(r0 + 4);
    acc[0] = fmaf(e0, x0.x, acc[0]); acc[1] = fmaf(e0, x0.y, acc[1]);
    acc[2] = fmaf(e0, x0.z, acc[2]); acc[3] = fmaf(e0, x0.w, acc[3]);
    acc[4] = fmaf(e0, y0.x, acc[4]); acc[5] = fmaf(e0, y0.y, acc[5]);
    acc[6] = fmaf(e0, y0.z, acc[6]); acc[7] = fmaf(e0, y0.w, acc[7]);
    den += e0;
  }
  float inv = 1.f / (den + EPS);
  float o[8];
#pragma unroll
  for (int j = 0; j < 8; ++j) {
    float v = acc[j] * inv;
    o[j] = v > 0.f ? v : expm1f(v);
  }
  float* w = xc + (size_t)n * F1 + lane * 8;
  *(float4*)w = make_float4(o[0], o[1], o[2], o[3]);
  *(float4*)(w + 4) = make_float4(o[4], o[5], o[6], o[7]);
}

// layer-2 CSR aggregation, fused score + finalize: one wave per node, lane = feature
__global__ __launch_bounds__(256) void k_agg2(const int* __restrict__ rows,
                                              const int* __restrict__ dst_s,
                                              const float* __restrict__ h2,
                                              const float* __restrict__ as_,
                                              const float* __restrict__ ad_,
                                              float* __restrict__ out) {
  int lane = threadIdx.x & 63;
  int n = (blockIdx.x * 256 + threadIdx.x) >> 6;
  if (n >= NND) return;
  const float asv = as_[n];
  int beg = rows[n], end = rows[n + 1];
  float acc = 0.f, den = 0.f;
  int i = beg;
  for (; i + 2 <= end; i += 2) {
    int d0 = dst_s[i], d1 = dst_s[i + 1];
    float s0 = asv + ad_[d0];
    float s1 = asv + ad_[d1];
    s0 = s0 >= 0.f ? s0 : ALPHA_SLOPE * s0;
    s1 = s1 >= 0.f ? s1 : ALPHA_SLOPE * s1;
    float e0 = __expf(-s0), e1 = __expf(-s1);
    float h0 = h2[(size_t)d0 * NCLS + lane];
    float h1v = h2[(size_t)d1 * NCLS + lane];
    acc = fmaf(e0, h0, acc);
    acc = fmaf(e1, h1v, acc);
    den += e0 + e1;
  }
  if (i < end) {
    int d0 = dst_s[i];
    float s0 = asv + ad_[d0];
    s0 = s0 >= 0.f ? s0 : ALPHA_SLOPE * s0;
    float e0 = __expf(-s0);
    acc = fmaf(e0, h2[(size_t)d0 * NCLS + lane], acc);
    den += e0;
  }
  float v = acc / (den + EPS);
  out[(size_t)n * NCLS + lane] = v >= 0.f ? v : OUT_SLOPE * v;
}

// ---------------- launcher ----------------
extern "C" void kernel_launch(void* const* d_in, const int* in_sizes, int n_in,
                              void* d_out, int out_size, void* d_ws, size_t ws_size,
                              hipStream_t stream) {
  const float* x       = (const float*)d_in[0];   // [B,N,256]
  const int*   ei      = (const int*)d_in[1];     // [B,2,E]
  const float* W_heads = (const float*)d_in[2];   // [8,256,64]
  const float* a_heads = (const float*)d_in[3];   // [8,128]
  const float* W_out   = (const float*)d_in[4];   // [512,64]
  const float* a_out   = (const float*)d_in[5];   // [128]
  float* out = (float*)d_out;

  float* ws = (float*)d_ws;
  float* Wcat = ws + OFF_WCAT;
  float* h1   = ws + OFF_H1;
  float* xc   = ws + OFF_XC;
  float* as1  = ws + OFF_AS1;
  float* ad1  = ws + OFF_AD1;
  float* h2   = ws + OFF_H2;
  float* as2  = ws + OFF_AS2;
  float* ad2  = ws + OFF_AD2;
  int* ib      = (int*)(ws + OFF_INT);
  int* counts  = ib + IOFF_COUNTS;
  int* rows    = ib + IOFF_ROWS;
  int* cursor  = ib + IOFF_CUR;
  int* dst_s   = ib + IOFF_DST;

  // weights rearrange (once)
  k_wcat<<<512, 256, 0, stream>>>(W_heads, Wcat);

  // ---- counting sort for all batches ----
  hipMemsetAsync(counts, 0, (size_t)NB * NND * sizeof(int), stream);
  k_hist<<<dim3((NED + 255) / 256, NB), 256, 0, stream>>>(ei, counts);
  k_scan<<<NB, 1024, 0, stream>>>(counts, rows, cursor);
  k_scatter<<<dim3((NED + 255) / 256, NB), 256, 0, stream>>>(ei, cursor, dst_s);

  for (int b = 0; b < NB; ++b) {
    const float* xb = x + (size_t)b * NND * NF;
    const int*   rb = rows + (size_t)b * (NND + 1);
    const int*   db = dst_s + (size_t)b * NED;
    float*       ob = out + (size_t)b * NND * NCLS;

    // layer 1: GEMM + fused alpha, then CSR agg with fused scores
    k_gemm_a<<<dim3((NND + BM - 1) / BM, F1 / BN), 256, 0, stream>>>(
        xb, Wcat, h1, NND, F1, NF, a_heads, as1, ad1, HEADS);
    k_agg1<<<(NND * 64 + 255) / 256, 256, 0, stream>>>(rb, db, h1, as1, ad1, xc);

    // layer 2
    k_gemm_a<<<dim3((NND + BM - 1) / BM, NCLS / BN), 256, 0, stream>>>(
        xc, W_out, h2, NND, NCLS, F1, a_out, as2, ad2, 1);
    k_agg2<<<(NND * 64 + 255) / 256, 256, 0, stream>>>(rb, db, h2, as2, ad2, ob);
  }
  (void)in_sizes; (void)n_in; (void)out_size; (void)ws_size;
}

// Round 5
// 840.324 us; speedup vs baseline: 4.9217x; 1.6861x over previous
//
#include <hip/hip_runtime.h>
#include <cstdint>
#include <cstddef>

// Problem shape (fixed by setup_inputs)
#define NND   10000     // nodes per graph
#define NED   160000    // edges per graph
#define NB    8         // batch
#define NF    256       // in features
#define NHID  64        // hidden per head
#define HEADS 8
#define F1    512       // HEADS*NHID
#define NCLS  64        // out classes

#define ALPHA_SLOPE 0.2f
#define OUT_SLOPE   0.01f
#define EPS         1e-16f

typedef unsigned short u16;
typedef short short8 __attribute__((ext_vector_type(8)));
typedef float f32x4 __attribute__((ext_vector_type(4)));

// ---------------- ws layout ----------------
// float region
static const size_t OFF_XC   = 0;                         // [N][512] f32
static const size_t OFF_AS1  = (size_t)NND * F1;          // [N][8]
static const size_t OFF_AD1  = OFF_AS1 + (size_t)NND * 8; // [N][8]
static const size_t OFF_AS2  = OFF_AD1 + (size_t)NND * 8; // [N]
static const size_t OFF_AD2  = OFF_AS2 + (size_t)NND;     // [N]
static const size_t OFF_US   = OFF_AD2 + (size_t)NND + 2; // ushort region (float-offset; +2 keeps 16B align: total 5300002? keep simple below)
// NOTE: recompute OFF_US to preserve 16B alignment (multiple of 4 floats):
//   NND*F1 + NND*8*2 + NND*2 = 5,120,000 + 160,000 + 20,000 = 5,300,000 (mult of 4) -> use that
static const size_t OFF_US_ALIGNED = (size_t)NND * F1 + (size_t)NND * 16 + (size_t)NND * 2; // 5,300,000
// ushort offsets (relative to ushort* base)
static const size_t U_WCHI = 0;                               // [512][256]
static const size_t U_WCLO = U_WCHI + (size_t)F1 * NF;        // [512][256]
static const size_t U_WOHI = U_WCLO + (size_t)F1 * NF;        // [64][512]
static const size_t U_WOLO = U_WOHI + (size_t)NCLS * F1;      // [64][512]
static const size_t U_H1   = U_WOLO + (size_t)NCLS * F1;      // [N][512]
static const size_t U_H2   = U_H1 + (size_t)NND * F1;         // [N][64]
static const size_t U_TOTAL = U_H2 + (size_t)NND * NCLS;      // ushorts
// int region starts after ushort region (in floats)
static const size_t OFF_INT = OFF_US_ALIGNED + (U_TOTAL + 1) / 2;
static const size_t IOFF_COUNTS = 0;                                 // [B][N]
static const size_t IOFF_ROWS   = IOFF_COUNTS + (size_t)NB * NND;    // [B][N+1]
static const size_t IOFF_CUR    = IOFF_ROWS + (size_t)NB * (NND + 1);// [B][N]
static const size_t IOFF_DST    = IOFF_CUR + (size_t)NB * NND;       // [B][E]

// ---------------- helpers ----------------
__device__ __forceinline__ u16 f32_to_bf16_rn(float f) {
  uint32_t u = __float_as_uint(f);
  uint32_t r = u + 0x7fffu + ((u >> 16) & 1u);
  return (u16)(r >> 16);
}
__device__ __forceinline__ float bf16_to_f32(u16 s) {
  return __uint_as_float((uint32_t)s << 16);
}
__device__ __forceinline__ void split1(float v, u16& h, u16& l) {
  h = f32_to_bf16_rn(v);
  float r = v - bf16_to_f32(h);
  l = f32_to_bf16_rn(r);
}

// ---------------- weight prep ----------------
// W_heads [8][256][64] -> WcatT hi/lo [512][256]  (n-major, k contiguous)
__global__ __launch_bounds__(256) void k_wsplit1(const float* __restrict__ Whd,
                                                 u16* __restrict__ hi,
                                                 u16* __restrict__ lo) {
  int idx = blockIdx.x * 256 + threadIdx.x;   // 512*256 total
  int n = idx >> 8, k = idx & 255;
  float v = Whd[(n >> 6) * (NF * NHID) + k * NHID + (n & 63)];
  u16 h, l; split1(v, h, l);
  hi[idx] = h; lo[idx] = l;
}
// W_out [512][64] -> WoT hi/lo [64][512]
__global__ __launch_bounds__(256) void k_wsplit2(const float* __restrict__ Wo,
                                                 u16* __restrict__ hi,
                                                 u16* __restrict__ lo) {
  int idx = blockIdx.x * 256 + threadIdx.x;   // 64*512 total
  int n = idx >> 9, k = idx & 511;
  float v = Wo[k * NCLS + n];
  u16 h, l; split1(v, h, l);
  hi[idx] = h; lo[idx] = l;
}

// ---------------- split-bf16 MFMA GEMM with fused alpha epilogue ----------------
// C[M, Nld](bf16) = A[M, KDIM](f32) * BT'[n][k] (pre-split bf16 hi/lo)
// Block: 256 thr = 4 waves; wave w does rows [w*MT*16, (w+1)*MT*16), 64 cols.
// BM = MT*64. grid.y selects the 64-col slice (== head for layer 1).
// Epilogue: as_[m*astr+h] = C[m][:]·avec[h*128 + 0:64]; ad_ with +64.
template<int MT, int KDIM>
__global__ __launch_bounds__(256) void k_gemm_mfma(
    const float* __restrict__ A,
    const u16* __restrict__ BThi, const u16* __restrict__ BTlo,
    u16* __restrict__ C, int M, int Nld,
    const float* __restrict__ avec,
    float* __restrict__ as_, float* __restrict__ ad_, int astr) {
  constexpr int BMm = MT * 64;
  __shared__ u16 As_hi[BMm][40];   // 80B pitch: b128 reads 2-way-conflict-free
  __shared__ u16 As_lo[BMm][40];
  __shared__ u16 Bs_hi[64][40];
  __shared__ u16 Bs_lo[64][40];

  const int tid = threadIdx.x;
  const int lane = tid & 63;
  const int w = tid >> 6;
  const int lm = lane & 15;          // col / row-in-tile selector
  const int lkg = lane >> 4;         // k-group 0..3
  const int m0 = blockIdx.x * BMm;
  const int hb = blockIdx.y;
  const int n0 = hb * 64;

  f32x4 acc[MT][4];
#pragma unroll
  for (int i = 0; i < MT; ++i)
#pragma unroll
    for (int j = 0; j < 4; ++j) acc[i][j] = 0.f;

  for (int kk = 0; kk < KDIM; kk += 32) {
    __syncthreads();
    // stage A (f32 -> split bf16)
#pragma unroll
    for (int u = 0; u < MT * 2; ++u) {
      int e = u * 256 + tid;          // float4 id; 8 per row
      int r = e >> 3;
      int kf = (e & 7) * 4;
      int gm = m0 + r;
      float4 v = make_float4(0.f, 0.f, 0.f, 0.f);
      if (gm < M) v = *(const float4*)(A + (size_t)gm * KDIM + kk + kf);
      ushort4 hv, lv;
      split1(v.x, hv.x, lv.x); split1(v.y, hv.y, lv.y);
      split1(v.z, hv.z, lv.z); split1(v.w, hv.w, lv.w);
      *(ushort4*)&As_hi[r][kf] = hv;
      *(ushort4*)&As_lo[r][kf] = lv;
    }
    // stage B (pre-split, n-major)
#pragma unroll
    for (int u = 0; u < 2; ++u) {
      int e = u * 256 + tid;          // 512 ushort4 per buffer
      int n = e >> 3;
      int kf = (e & 7) * 4;
      size_t g = (size_t)(n0 + n) * KDIM + kk + kf;
      *(ushort4*)&Bs_hi[n][kf] = *(const ushort4*)(BThi + g);
      *(ushort4*)&Bs_lo[n][kf] = *(const ushort4*)(BTlo + g);
    }
    __syncthreads();

    short8 ah[MT], al[MT], bh[4], bl[4];
#pragma unroll
    for (int mi = 0; mi < MT; ++mi) {
      int row = w * (MT * 16) + mi * 16 + lm;
      ah[mi] = *(const short8*)&As_hi[row][lkg * 8];
      al[mi] = *(const short8*)&As_lo[row][lkg * 8];
    }
#pragma unroll
    for (int nj = 0; nj < 4; ++nj) {
      int row = nj * 16 + lm;
      bh[nj] = *(const short8*)&Bs_hi[row][lkg * 8];
      bl[nj] = *(const short8*)&Bs_lo[row][lkg * 8];
    }
#pragma unroll
    for (int mi = 0; mi < MT; ++mi)
#pragma unroll
      for (int nj = 0; nj < 4; ++nj) {
        acc[mi][nj] = __builtin_amdgcn_mfma_f32_16x16x32_bf16(ah[mi], bh[nj], acc[mi][nj], 0, 0, 0);
        acc[mi][nj] = __builtin_amdgcn_mfma_f32_16x16x32_bf16(ah[mi], bl[nj], acc[mi][nj], 0, 0, 0);
        acc[mi][nj] = __builtin_amdgcn_mfma_f32_16x16x32_bf16(al[mi], bh[nj], acc[mi][nj], 0, 0, 0);
      }
  }

  // epilogue: C (bf16) + alpha projections (f32-exact from accs)
  float a_sv[4], a_dv[4];
#pragma unroll
  for (int nj = 0; nj < 4; ++nj) {
    a_sv[nj] = avec[hb * 128 + nj * 16 + lm];
    a_dv[nj] = avec[hb * 128 + 64 + nj * 16 + lm];
  }
#pragma unroll
  for (int mi = 0; mi < MT; ++mi) {
#pragma unroll
    for (int r = 0; r < 4; ++r) {
      int gm = m0 + w * (MT * 16) + mi * 16 + lkg * 4 + r;
      float ps = acc[mi][0][r] * a_sv[0] + acc[mi][1][r] * a_sv[1] +
                 acc[mi][2][r] * a_sv[2] + acc[mi][3][r] * a_sv[3];
      float pd = acc[mi][0][r] * a_dv[0] + acc[mi][1][r] * a_dv[1] +
                 acc[mi][2][r] * a_dv[2] + acc[mi][3][r] * a_dv[3];
#pragma unroll
      for (int off = 1; off < 16; off <<= 1) {
        ps += __shfl_xor(ps, off, 16);
        pd += __shfl_xor(pd, off, 16);
      }
      if (gm < M) {
#pragma unroll
        for (int nj = 0; nj < 4; ++nj)
          C[(size_t)gm * Nld + n0 + nj * 16 + lm] = f32_to_bf16_rn(acc[mi][nj][r]);
        if (lm == 0) {
          as_[(size_t)gm * astr + hb] = ps;
          ad_[(size_t)gm * astr + hb] = pd;
        }
      }
    }
  }
}

// ---- counting sort (all batches in one launch each) ----

__global__ __launch_bounds__(256) void k_hist(const int* __restrict__ ei,
                                              int* __restrict__ counts) {
  int b = blockIdx.y;
  int e = blockIdx.x * 256 + threadIdx.x;
  if (e < NED) {
    int s = ei[(size_t)b * 2 * NED + e];
    atomicAdd(&counts[b * NND + s], 1);
  }
}

// seq-10-per-thread + one 1024-wide LDS scan; one block per batch
__global__ __launch_bounds__(1024) void k_scan(const int* __restrict__ counts,
                                               int* __restrict__ rows,
                                               int* __restrict__ cursor) {
  __shared__ int lds[1024];
  const int b = blockIdx.x;
  const int tid = threadIdx.x;
  const int* cb = counts + b * NND;
  int* rb = rows + b * (NND + 1);
  int* ub = cursor + b * NND;
  int v[10];
  int s = 0;
  int base = tid * 10;
#pragma unroll
  for (int j = 0; j < 10; ++j) {
    int i = base + j;
    v[j] = (i < NND) ? cb[i] : 0;
    s += v[j];
  }
  lds[tid] = s;
  __syncthreads();
  for (int off = 1; off < 1024; off <<= 1) {
    int t = (tid >= off) ? lds[tid - off] : 0;
    __syncthreads();
    lds[tid] += t;
    __syncthreads();
  }
  int run = lds[tid] - s;   // exclusive prefix
#pragma unroll
  for (int j = 0; j < 10; ++j) {
    int i = base + j;
    if (i < NND) { rb[i] = run; ub[i] = run; }
    run += v[j];
  }
  if (tid == 1023) rb[NND] = run;
}

// scatter dst into src-sorted order (dst only; src == segment id in CSR)
__global__ __launch_bounds__(256) void k_scatter(const int* __restrict__ ei,
                                                 int* __restrict__ cursor,
                                                 int* __restrict__ dst_s) {
  int b = blockIdx.y;
  int e = blockIdx.x * 256 + threadIdx.x;
  if (e < NED) {
    int s = ei[(size_t)b * 2 * NED + e];
    int d = ei[(size_t)b * 2 * NED + NED + e];
    int pos = atomicAdd(&cursor[b * NND + s], 1);
    dst_s[(size_t)b * NED + pos] = d;
  }
}

#define UPK8(q, e) do { \
  acc[0] = fmaf(e, __uint_as_float((q).x << 16), acc[0]); \
  acc[1] = fmaf(e, __uint_as_float((q).x & 0xffff0000u), acc[1]); \
  acc[2] = fmaf(e, __uint_as_float((q).y << 16), acc[2]); \
  acc[3] = fmaf(e, __uint_as_float((q).y & 0xffff0000u), acc[3]); \
  acc[4] = fmaf(e, __uint_as_float((q).z << 16), acc[4]); \
  acc[5] = fmaf(e, __uint_as_float((q).z & 0xffff0000u), acc[5]); \
  acc[6] = fmaf(e, __uint_as_float((q).w << 16), acc[6]); \
  acc[7] = fmaf(e, __uint_as_float((q).w & 0xffff0000u), acc[7]); \
} while (0)

// layer-1 CSR aggregation, fused score + finalize: one wave per node.
// lane l owns features l*8..l*8+7 (16B of the bf16 h1 row), head = l>>3.
__global__ __launch_bounds__(256) void k_agg1(const int* __restrict__ rows,
                                              const int* __restrict__ dst_s,
                                              const u16* __restrict__ h1,
                                              const float* __restrict__ as_,
                                              const float* __restrict__ ad_,
                                              float* __restrict__ xc) {
  int lane = threadIdx.x & 63;
  int n = (blockIdx.x * 256 + threadIdx.x) >> 6;
  if (n >= NND) return;
  const int hh = lane >> 3;
  const float asv = as_[n * 8 + hh];
  int beg = rows[n], end = rows[n + 1];
  float acc[8] = {};
  float den = 0.f;
  int i = beg;
  for (; i + 2 <= end; i += 2) {
    int d0 = dst_s[i], d1 = dst_s[i + 1];
    float s0 = asv + ad_[d0 * 8 + hh];
    float s1 = asv + ad_[d1 * 8 + hh];
    s0 = s0 >= 0.f ? s0 : ALPHA_SLOPE * s0;
    s1 = s1 >= 0.f ? s1 : ALPHA_SLOPE * s1;
    float e0 = __expf(-s0), e1 = __expf(-s1);
    uint4 q0 = *((const uint4*)(h1 + (size_t)d0 * F1) + lane);
    uint4 q1 = *((const uint4*)(h1 + (size_t)d1 * F1) + lane);
    UPK8(q0, e0);
    UPK8(q1, e1);
    den += e0 + e1;
  }
  if (i < end) {
    int d0 = dst_s[i];
    float s0 = asv + ad_[d0 * 8 + hh];
    s0 = s0 >= 0.f ? s0 : ALPHA_SLOPE * s0;
    float e0 = __expf(-s0);
    uint4 q0 = *((const uint4*)(h1 + (size_t)d0 * F1) + lane);
    UPK8(q0, e0);
    den += e0;
  }
  float inv = 1.f / (den + EPS);
  float o[8];
#pragma unroll
  for (int j = 0; j < 8; ++j) {
    float v = acc[j] * inv;
    o[j] = v > 0.f ? v : expm1f(v);
  }
  float* wp = xc + (size_t)n * F1 + lane * 8;
  *(float4*)wp = make_float4(o[0], o[1], o[2], o[3]);
  *(float4*)(wp + 4) = make_float4(o[4], o[5], o[6], o[7]);
}

// layer-2 CSR aggregation, fused score + finalize: one wave per node, lane = feature
__global__ __launch_bounds__(256) void k_agg2(const int* __restrict__ rows,
                                              const int* __restrict__ dst_s,
                                              const u16* __restrict__ h2,
                                              const float* __restrict__ as_,
                                              const float* __restrict__ ad_,
                                              float* __restrict__ out) {
  int lane = threadIdx.x & 63;
  int n = (blockIdx.x * 256 + threadIdx.x) >> 6;
  if (n >= NND) return;
  const float asv = as_[n];
  int beg = rows[n], end = rows[n + 1];
  float acc = 0.f, den = 0.f;
  int i = beg;
  for (; i + 2 <= end; i += 2) {
    int d0 = dst_s[i], d1 = dst_s[i + 1];
    float s0 = asv + ad_[d0];
    float s1 = asv + ad_[d1];
    s0 = s0 >= 0.f ? s0 : ALPHA_SLOPE * s0;
    s1 = s1 >= 0.f ? s1 : ALPHA_SLOPE * s1;
    float e0 = __expf(-s0), e1 = __expf(-s1);
    float h0 = bf16_to_f32(h2[(size_t)d0 * NCLS + lane]);
    float h1v = bf16_to_f32(h2[(size_t)d1 * NCLS + lane]);
    acc = fmaf(e0, h0, acc);
    acc = fmaf(e1, h1v, acc);
    den += e0 + e1;
  }
  if (i < end) {
    int d0 = dst_s[i];
    float s0 = asv + ad_[d0];
    s0 = s0 >= 0.f ? s0 : ALPHA_SLOPE * s0;
    float e0 = __expf(-s0);
    acc = fmaf(e0, bf16_to_f32(h2[(size_t)d0 * NCLS + lane]), acc);
    den += e0;
  }
  float v = acc / (den + EPS);
  out[(size_t)n * NCLS + lane] = v >= 0.f ? v : OUT_SLOPE * v;
}

// ---------------- launcher ----------------
extern "C" void kernel_launch(void* const* d_in, const int* in_sizes, int n_in,
                              void* d_out, int out_size, void* d_ws, size_t ws_size,
                              hipStream_t stream) {
  const float* x       = (const float*)d_in[0];   // [B,N,256]
  const int*   ei      = (const int*)d_in[1];     // [B,2,E]
  const float* W_heads = (const float*)d_in[2];   // [8,256,64]
  const float* a_heads = (const float*)d_in[3];   // [8,128]
  const float* W_out   = (const float*)d_in[4];   // [512,64]
  const float* a_out   = (const float*)d_in[5];   // [128]
  float* out = (float*)d_out;

  float* ws = (float*)d_ws;
  float* xc  = ws + OFF_XC;
  float* as1 = ws + OFF_AS1;
  float* ad1 = ws + OFF_AD1;
  float* as2 = ws + OFF_AS2;
  float* ad2 = ws + OFF_AD2;
  u16* ub = (u16*)(ws + OFF_US_ALIGNED);
  u16* wchi = ub + U_WCHI;
  u16* wclo = ub + U_WCLO;
  u16* wohi = ub + U_WOHI;
  u16* wolo = ub + U_WOLO;
  u16* h1   = ub + U_H1;
  u16* h2   = ub + U_H2;
  int* ib     = (int*)(ws + OFF_INT);
  int* counts = ib + IOFF_COUNTS;
  int* rows   = ib + IOFF_ROWS;
  int* cursor = ib + IOFF_CUR;
  int* dst_s  = ib + IOFF_DST;

  // weight prep (once per call)
  k_wsplit1<<<(F1 * NF) / 256, 256, 0, stream>>>(W_heads, wchi, wclo);
  k_wsplit2<<<(NCLS * F1) / 256, 256, 0, stream>>>(W_out, wohi, wolo);

  // ---- counting sort for all batches ----
  hipMemsetAsync(counts, 0, (size_t)NB * NND * sizeof(int), stream);
  k_hist<<<dim3((NED + 255) / 256, NB), 256, 0, stream>>>(ei, counts);
  k_scan<<<NB, 1024, 0, stream>>>(counts, rows, cursor);
  k_scatter<<<dim3((NED + 255) / 256, NB), 256, 0, stream>>>(ei, cursor, dst_s);

  for (int b = 0; b < NB; ++b) {
    const float* xb = x + (size_t)b * NND * NF;
    const int*   rb = rows + (size_t)b * (NND + 1);
    const int*   db = dst_s + (size_t)b * NED;
    float*       ob = out + (size_t)b * NND * NCLS;

    // layer 1: split-bf16 MFMA GEMM (+alpha) -> bf16 h1; CSR agg -> f32 xc
    k_gemm_mfma<2, NF><<<dim3((NND + 127) / 128, HEADS), 256, 0, stream>>>(
        xb, wchi, wclo, h1, NND, F1, a_heads, as1, ad1, HEADS);
    k_agg1<<<(NND * 64 + 255) / 256, 256, 0, stream>>>(rb, db, h1, as1, ad1, xc);

    // layer 2
    k_gemm_mfma<1, F1><<<dim3((NND + 63) / 64, 1), 256, 0, stream>>>(
        xc, wohi, wolo, h2, NND, NCLS, a_out, as2, ad2, 1);
    k_agg2<<<(NND * 64 + 255) / 256, 256, 0, stream>>>(rb, db, h2, as2, ad2, ob);
  }
  (void)in_sizes; (void)n_in; (void)out_size; (void)ws_size;
}